// Round 4
// baseline (832.660 us; speedup 1.0000x reference)
//
#include <hip/hip_runtime.h>
#include <stdint.h>

#define NROW 8192          // N
#define DDIM 512           // D
#define BB   8             // B
#define PP   4             // P
#define MTOT (BB*NROW)     // 65536 rows

typedef __attribute__((ext_vector_type(8))) short short8;            // 8 bf16 (4 VGPRs)
typedef __attribute__((ext_vector_type(4))) float floatx4;
typedef __attribute__((ext_vector_type(4))) unsigned int uintx4;

// ---- bf16 helpers ----
__device__ inline float bf2f(unsigned short h) { return __uint_as_float(((unsigned)h) << 16); }
__device__ inline unsigned short f2bf_rn(float f) {
    return (unsigned short)((__float_as_uint(f) + 0x8000u) >> 16);   // round-half-up
}
__device__ inline unsigned pack_bf16(float a, float b) {
    unsigned ua = __float_as_uint(a) + 0x8000u;
    unsigned ub = __float_as_uint(b) + 0x8000u;
    return __builtin_amdgcn_perm(ub, ua, 0x07060302u);
}
__device__ inline uintx4 packA(const floatx4& v0, const floatx4& v1) {
    uintx4 w = { pack_bf16(v0[0], v0[1]), pack_bf16(v0[2], v0[3]),
                 pack_bf16(v1[0], v1[1]), pack_bf16(v1[2], v1[3]) };
    return w;
}

template <typename T> __device__ inline float loadF(const T* p);
template <> __device__ inline float loadF<float>(const float* p) { return *p; }
template <> __device__ inline float loadF<unsigned short>(const unsigned short* p) { return bf2f(*p); }

// async global->LDS, 16B per lane; LDS dest = wave-uniform base + lane*16
__device__ inline void glds16(const void* g, void* l) {
    __builtin_amdgcn_global_load_lds(
        (const __attribute__((address_space(1))) void*)g,
        (__attribute__((address_space(3))) void*)l, 16, 0, 0);
}

// counted-vmcnt barrier: drain LDS ops + all but N outstanding VMEM ops,
// then s_barrier. Keeps deep prefetches in flight across the barrier (T4).
#define SYNC_VM(N) do {                                                 \
    __builtin_amdgcn_sched_barrier(0);                                  \
    asm volatile("s_waitcnt vmcnt(" #N ") lgkmcnt(0)" ::: "memory");    \
    __builtin_amdgcn_s_barrier();                                       \
    __builtin_amdgcn_sched_barrier(0);                                  \
} while (0)

// ---- histogram: cnt[i][r] = multiplicity of r in groups[i] ----
__global__ void hist_kernel(const int* __restrict__ groups, float* __restrict__ cnt) {
    int t = blockIdx.x * 256 + threadIdx.x;     // 0..32767
    int i = t >> 13;
    atomicAdd(&cnt[i * NROW + groups[t]], 1.0f);
}

// ---- W -> bf16, pre-swizzled into MFMA B-fragment order ----
// Wsw[i][kb 0..15][gtile 0..31][lane 0..63][e 0..7] = bf16(W[i][k][n])
//   n = gtile*16 + (lane&15), k = kb*32 + (lane>>4)*8 + e
__global__ void transpose_w(const float* __restrict__ W, unsigned short* __restrict__ Wsw) {
    int u = blockIdx.x * 256 + threadIdx.x;     // 0..131071 (one 16B chunk each)
    int i    = u >> 15;
    int kb   = (u >> 11) & 15;
    int gt   = (u >> 6) & 31;
    int lane = u & 63;
    int n  = gt * 16 + (lane & 15);
    int k0 = kb * 32 + (lane >> 4) * 8;
    const float* wp = W + i * 262144 + k0 * 512 + n;
    unsigned hp[4];
    #pragma unroll
    for (int j = 0; j < 4; ++j)
        hp[j] = pack_bf16(wp[(2*j) * 512], wp[(2*j+1) * 512]);
    uintx4 w = {hp[0], hp[1], hp[2], hp[3]};
    *(uintx4*)(Wsw + (size_t)u * 8) = w;
}

// ---- x (fp32) -> bf16, same rounding as pack path ----
__global__ void cvt_bf16(const float* __restrict__ x, unsigned short* __restrict__ xb) {
    size_t t = (size_t)blockIdx.x * 256 + threadIdx.x;   // 8 elems each
    const floatx4* p = (const floatx4*)x + t * 2;
    floatx4 v0 = p[0], v1 = p[1];
    *(uintx4*)(xb + t * 8) = packA(v0, v1);
}

// ---- fused round GEMM, wave-per-i, deep async pipeline ----
// Block: 64x64 output tile; wave w accumulates UNSCALED srcA@W_w over K=512.
// Per-row scale c_w[m] applied once to f32 acc in epilogue; waves combined
// through LDS:  dst = add + scale * sum_w c_w[m] * (srcA @ W_w)[m,n]
// A: bf16, tri-buffered LDS via global_load_lds, issued 2 iterations ahead,
//    drained by counted vmcnt at the barrier (loads live across barriers).
// B: fragment-direct from L2-resident Wsw, 4-slot ring (~1.5 iter lead).
// 8 iterations x 2 subs x 16 MFMA; exactly one barrier per iteration.
template <typename AddT, bool WF32, bool WBF16>
__global__ __launch_bounds__(256, 2)
void gemm_round(const unsigned short* __restrict__ srcA, const AddT* __restrict__ srcAdd,
                const unsigned short* __restrict__ Wsw, const float* __restrict__ cnt,
                float* __restrict__ dstF, unsigned short* __restrict__ dstB, float scale)
{
    __shared__ __align__(16) unsigned char smem[24576];  // sA tri-buf [3][2][4096B]
    float* sE = (float*)smem;                            // epilogue overlay [4][16][69]

    const int t    = threadIdx.x;
    const int wave = t >> 6;                 // wave == i
    const int lane = t & 63;
    const int nb   = blockIdx.x;             // 0..7, fastest-varying
    const int m0   = blockIdx.y * 64;

    // A staging: thread t stages 16B = 8 bf16 of row (wave*16 + (lane&15)),
    // k-chunk ((lane>>4)&3)*8 within each 32-wide sub. LDS slot = t*16B.
    const int srow = (wave << 4) | (lane & 15);
    const int scol = ((lane >> 4) & 3) * 8;
    const unsigned short* sp = srcA + (size_t)(m0 + srow) * DDIM + scol;

    // B fragment base: Wsw[((wave*16+kb)*32 + nb*4 + b)*512 + lane*8]
    const unsigned short* bp = Wsw + ((size_t)(wave * 16) * 32 + nb * 4) * 512 + lane * 8;

    floatx4 acc[4][4] = {};
    short8 Bf[4][4];          // 4-slot ring, slot = sub & 3

    // issue 2 glds for iteration it2 into tri-buffer buf (wave-uniform LDS base)
    auto stage = [&](int buf, int it2) {
        #pragma unroll
        for (int s = 0; s < 2; ++s)
            glds16(sp + (2 * it2 + s) * 32, smem + (buf * 2 + s) * 4096 + wave * 1024);
    };
    auto loadB = [&](int slot, int s) {
        #pragma unroll
        for (int b = 0; b < 4; ++b)
            Bf[slot][b] = *(const short8*)(bp + (size_t)s * 16384 + b * 512);
    };

    // ---- prologue: A for it=0,1; B for subs 0,1,2
    stage(0, 0);
    stage(1, 1);
    __builtin_amdgcn_sched_barrier(0);
    loadB(0, 0); loadB(1, 1); loadB(2, 2);
    SYNC_VM(14);                       // drain stage(0); keep stage(1)+12 B in flight

    #pragma unroll
    for (int it = 0; it < 8; ++it) {
        const unsigned short* sAr = (const unsigned short*)(smem + (it % 3) * 8192);

        // both subs' A fragments (conflict-free lane-contiguous b128)
        short8 af[2][4];
        #pragma unroll
        for (int s = 0; s < 2; ++s)
            #pragma unroll
            for (int a = 0; a < 4; ++a)
                af[s][a] = *(const short8*)(sAr + s * 2048 + (a * 64 + lane) * 8);

        if (it < 6) stage((it + 2) % 3, it + 2);     // A two iterations ahead
        __builtin_amdgcn_sched_barrier(0);
        if (it < 7) loadB((2 * it + 3) & 3, 2 * it + 3);
        __builtin_amdgcn_sched_barrier(0);

        // sub0
        #pragma unroll
        for (int a = 0; a < 4; ++a)
            #pragma unroll
            for (int b = 0; b < 4; ++b)
                acc[a][b] = __builtin_amdgcn_mfma_f32_16x16x32_bf16(af[0][a], Bf[(2 * it) & 3][b], acc[a][b], 0, 0, 0);

        if (it < 6) loadB((2 * it + 4) & 3, 2 * it + 4);
        __builtin_amdgcn_sched_barrier(0);

        // sub1
        #pragma unroll
        for (int a = 0; a < 4; ++a)
            #pragma unroll
            for (int b = 0; b < 4; ++b)
                acc[a][b] = __builtin_amdgcn_mfma_f32_16x16x32_bf16(af[1][a], Bf[(2 * it + 1) & 3][b], acc[a][b], 0, 0, 0);

        // barrier: drain the glds for it+1 (issued last iter), keep the rest
        if (it < 6)       SYNC_VM(10);   // stage(it+2)=2 + B(2it+3)=4 + B(2it+4)=4
        else if (it == 6) SYNC_VM(4);    // only B(15) in flight; drains stage(7)
        else              SYNC_VM(0);    // full drain before epilogue overlay
    }

    // ---- epilogue: scale own acc by c_i[row], combine 4 waves through LDS
    // sE overlays sA (dead after final barrier). Row stride 69 avoids conflicts.
    float cs[4][4];
    #pragma unroll
    for (int a = 0; a < 4; ++a)
        #pragma unroll
        for (int q = 0; q < 4; ++q)
            cs[a][q] = cnt[wave * NROW + ((m0 + a * 16 + (lane >> 4) * 4 + q) & (NROW - 1))];

    #pragma unroll
    for (int a = 0; a < 4; ++a) {
        float* se = sE + wave * 1104;            // 16*69 floats per wave region
        #pragma unroll
        for (int b = 0; b < 4; ++b)
            #pragma unroll
            for (int q = 0; q < 4; ++q)
                se[((lane >> 4) * 4 + q) * 69 + b * 16 + (lane & 15)] = acc[a][b][q] * cs[a][q];
        __syncthreads();
        #pragma unroll
        for (int e = 0; e < 4; ++e) {
            const int r = wave * 4 + e;
            const size_t m = (size_t)(m0 + a * 16 + r);
            const size_t n = (size_t)nb * 64 + lane;
            const float sum = sE[0 * 1104 + r * 69 + lane] + sE[1 * 1104 + r * 69 + lane]
                            + sE[2 * 1104 + r * 69 + lane] + sE[3 * 1104 + r * 69 + lane];
            const float f = loadF(srcAdd + m * DDIM + n) + scale * sum;
            if constexpr (WF32)  dstF[m * DDIM + n] = f;
            if constexpr (WBF16) dstB[m * DDIM + n] = f2bf_rn(f);
        }
        if (a < 3) __syncthreads();
    }
}

extern "C" void kernel_launch(void* const* d_in, const int* in_sizes, int n_in,
                              void* d_out, int out_size, void* d_ws, size_t ws_size,
                              hipStream_t stream) {
    const float* x      = (const float*)d_in[0];   // (8, 8192, 512) fp32
    const float* W      = (const float*)d_in[1];   // (4, 512, 512) fp32
    const int*   groups = (const int*)d_in[2];     // (4, 512, 16) int32
    float* out = (float*)d_out;                    // (8, 8192, 512) fp32

    char* ws = (char*)d_ws;
    float*          cnt = (float*)ws;                               // 128 KB
    unsigned short* Wsw = (unsigned short*)(ws + 131072);           // 2 MB
    unsigned short* U1  = (unsigned short*)(ws + 131072 + 2097152); // 64 MB bf16
    unsigned short* U2  = U1 + (size_t)MTOT * DDIM;                 // 64 MB bf16 (aliases xb)

    hipMemsetAsync(cnt, 0, PP * NROW * sizeof(float), stream);
    hist_kernel<<<32768 / 256, 256, 0, stream>>>(groups, cnt);
    transpose_w<<<131072 / 256, 256, 0, stream>>>(W, Wsw);
    cvt_bf16<<<(MTOT * DDIM / 8) / 256, 256, 0, stream>>>(x, U2);   // xb = U2 slot

    // nb fastest-varying: 8 blocks sharing an A-tile dispatch together
    dim3 grid(DDIM / 64, MTOT / 64);               // (8, 1024)
    // round 1: A=bf16(x), add=x (fp32) -> out (fp32) + U1 (bf16)
    gemm_round<float, true, true><<<grid, 256, 0, stream>>>(U2, x, Wsw, cnt, out, U1, 1.0f);
    // round 2: A=U1, add=out (fp32) -> U2 (bf16; xb is dead)
    gemm_round<float, false, true><<<grid, 256, 0, stream>>>(U1, out, Wsw, cnt, nullptr, U2, 0.5f);
    // round 3: A=U2, add=U2 (bf16) -> out (fp32)
    gemm_round<unsigned short, true, false><<<grid, 256, 0, stream>>>(U2, U2, Wsw, cnt, out, nullptr, 1.0f / 3.0f);
}